// Round 3
// baseline (198.572 us; speedup 1.0000x reference)
//
#include <hip/hip_runtime.h>

// Problem dims (fixed by reference)
#define Bq 32
#define Sq 64
#define Iq 256
#define Hq 256
#define Oq 128
#define Fq 512          // Iq + Hq
#define WPB 8           // workgroups per batch
#define NT 512          // threads per workgroup

// tanh via v_exp_f32: 1 - 2/(e^{2x}+1). Saturates to +/-1 at +/-inf (no NaN).
__device__ __forceinline__ float fast_tanh(float v) {
    const float e = __expf(2.0f * v);
    return 1.0f - __fdividef(2.0f, e + 1.0f);
}

// Critical-path-split persistent RNN.
// Mapping: 32 rows/wg, 16 lanes/row; lane owns cols 4*lr + 64*j, j=0..7
// (j<4 -> x columns, j>=4 -> h columns).
// Per step t the ONLY post-h-arrival work is: 16 fma (h-part of pre) +
// 4-shuffle butterfly + fast_tanh + publish. Everything else (f update,
// tw=w+f, nsq, inv, x-part of pre for t+1) runs in the shadow phase that
// overlaps the publish->poll L2 latency of peer workgroups.
__global__ __launch_bounds__(NT, 2) void stpn_main(
    const float* __restrict__ x,     // (B,S,I)
    const float* __restrict__ w,     // (H,F)
    const float* __restrict__ wl,    // (H,F)
    const float* __restrict__ wgm,   // (H,F)
    const float* __restrict__ bias,  // (H)
    float* __restrict__ out,         // [tag(B*O) | h_fin(B*H) | f_fin(B*H*F)]
    unsigned long long* __restrict__ hb) // [2][B][H] (tag<<32|bits) slots
{
    const int blk   = blockIdx.x;
    const int b     = blk & 31;       // all 8 wgs of a batch land on XCD b%8
    const int chunk = blk >> 5;       // 0..7
    const int h0    = chunk * 32;
    const int tid   = threadIdx.x;
    const int lr    = tid & 15;       // lane within row
    const int r     = tid >> 4;       // row 0..31
    const int row   = h0 + r;

    __shared__ float xls[2][Iq];      // double-buffered x_t
    __shared__ float hls[2][Hq];      // double-buffered h_{t-1}

    // Static params + fast-weight state in registers for all 64 steps.
    float fw[32], fl[32], fg[32], ff[32];
    const size_t rowoff = (size_t)row * Fq;
#pragma unroll
    for (int j = 0; j < 8; ++j) {
        const int c = 4 * lr + 64 * j;
        *(float4*)&fw[4*j] = *(const float4*)(w   + rowoff + c);
        *(float4*)&fl[4*j] = *(const float4*)(wl  + rowoff + c);
        *(float4*)&fg[4*j] = *(const float4*)(wgm + rowoff + c);
    }
#pragma unroll
    for (int j = 0; j < 32; ++j) ff[j] = 0.f;

    const float brow = bias[row];
    const float* xb = x + (size_t)b * Sq * Iq;

    // ---- Prologue: x_0 -> LDS, stage x_1 in reg; initial shadow for t=0 ----
    float xr = 0.f;
    if (tid < Iq) {
        xls[0][tid] = xb[tid];          // x_0
        xr = xb[Iq + tid];              // x_1
    }
    __syncthreads();

    float tw_h[16];                     // tw for h-columns (carried to critical)
    float xv[16];                       // x_t values at my columns (carried)
    float nsq = 0.f, xpre = 0.f;
#pragma unroll
    for (int j = 0; j < 4; ++j) {       // x columns: tw = fw (f=0)
        const float4 x4 = *(const float4*)&xls[0][4 * lr + 64 * j];
        *(float4*)&xv[4*j] = x4;
        float tw;
        tw = fw[4*j+0]; nsq = fmaf(tw, tw, nsq); xpre = fmaf(x4.x, tw, xpre);
        tw = fw[4*j+1]; nsq = fmaf(tw, tw, nsq); xpre = fmaf(x4.y, tw, xpre);
        tw = fw[4*j+2]; nsq = fmaf(tw, tw, nsq); xpre = fmaf(x4.z, tw, xpre);
        tw = fw[4*j+3]; nsq = fmaf(tw, tw, nsq); xpre = fmaf(x4.w, tw, xpre);
    }
#pragma unroll
    for (int j = 0; j < 16; ++j) {      // h columns
        const float tw = fw[16 + j];
        tw_h[j] = tw; nsq = fmaf(tw, tw, nsq);
    }
#pragma unroll
    for (int m = 1; m < 16; m <<= 1) nsq += __shfl_xor(nsq, m, 16);
    float inv = __fdividef(1.0f, sqrtf(nsq) + 1e-16f);

    for (int t = 0; t < Sq; ++t) {
        const int pp = (t - 1) & 1;     // h-buffer parity for step t-1
        // ---- pre-barrier staging ----
        if (tid < Iq) {
            if (t + 1 < Sq) xls[(t + 1) & 1][tid] = xr;     // x_{t+1} -> LDS
            if (t + 2 < Sq) xr = xb[(size_t)(t + 2) * Iq + tid];
        } else {
            const int hh = tid - Iq;
            if (t > 0 && (hh < h0 || hh >= h0 + 32)) {      // remote rows only
                unsigned long long* slot =
                    hb + (size_t)pp * Bq * Hq + (size_t)b * Hq + hh;
                unsigned long long v;
                do {
                    v = __hip_atomic_load(slot, __ATOMIC_RELAXED,
                                          __HIP_MEMORY_SCOPE_AGENT);
                } while ((unsigned)(v >> 32) != (unsigned)t);
                hls[pp][hh] = __uint_as_float((unsigned)(v & 0xffffffffu));
            }
        }
        __syncthreads();                 // the only barrier per step

        // ---- critical: h-part of pre -> reduce -> tanh -> publish ----
        float hv[16];
        float pre = xpre;
        if (t > 0) {
#pragma unroll
            for (int j = 0; j < 4; ++j) {
                const float4 h4 = *(const float4*)&hls[pp][4 * lr + 64 * j];
                *(float4*)&hv[4*j] = h4;
                pre = fmaf(h4.x, tw_h[4*j+0], pre);
                pre = fmaf(h4.y, tw_h[4*j+1], pre);
                pre = fmaf(h4.z, tw_h[4*j+2], pre);
                pre = fmaf(h4.w, tw_h[4*j+3], pre);
            }
        } else {
#pragma unroll
            for (int j = 0; j < 16; ++j) hv[j] = 0.f;
        }
#pragma unroll
        for (int m = 1; m < 16; m <<= 1) pre += __shfl_xor(pre, m, 16);
        const float hn = fast_tanh(fmaf(pre, inv, brow));

        if (lr == 0) {
            if (t < Sq - 1) {
                hls[t & 1][row] = hn;    // local fast path for own rows
                const unsigned long long pk =
                    ((unsigned long long)(unsigned)(t + 1) << 32) |
                    (unsigned long long)__float_as_uint(hn);
                __hip_atomic_store(
                    hb + (size_t)(t & 1) * Bq * Hq + (size_t)b * Hq + row, pk,
                    __ATOMIC_RELAXED, __HIP_MEMORY_SCOPE_AGENT);
            } else {
                out[Bq * Oq + (size_t)b * Hq + row] = hn;   // h_fin
            }
        }

        // ---- shadow: f update, then tw/nsq/inv/xpre for step t+1 ----
#pragma unroll
        for (int j = 0; j < 16; ++j)     // x columns
            ff[j] = fmaf(fl[j], ff[j] * inv, fg[j] * (hn * xv[j]));
#pragma unroll
        for (int j = 0; j < 16; ++j)     // h columns
            ff[16+j] = fmaf(fl[16+j], ff[16+j] * inv, fg[16+j] * (hn * hv[j]));

        if (t < Sq - 1) {
            const int q = (t + 1) & 1;
            nsq = 0.f; xpre = 0.f;
#pragma unroll
            for (int j = 0; j < 4; ++j) {
                const float4 x4 = *(const float4*)&xls[q][4 * lr + 64 * j];
                *(float4*)&xv[4*j] = x4;
                float tw;
                tw = fw[4*j+0] + ff[4*j+0]; nsq = fmaf(tw, tw, nsq); xpre = fmaf(x4.x, tw, xpre);
                tw = fw[4*j+1] + ff[4*j+1]; nsq = fmaf(tw, tw, nsq); xpre = fmaf(x4.y, tw, xpre);
                tw = fw[4*j+2] + ff[4*j+2]; nsq = fmaf(tw, tw, nsq); xpre = fmaf(x4.z, tw, xpre);
                tw = fw[4*j+3] + ff[4*j+3]; nsq = fmaf(tw, tw, nsq); xpre = fmaf(x4.w, tw, xpre);
            }
#pragma unroll
            for (int j = 0; j < 16; ++j) {
                const float tw = fw[16+j] + ff[16+j];
                tw_h[j] = tw; nsq = fmaf(tw, tw, nsq);
            }
#pragma unroll
            for (int m = 1; m < 16; m <<= 1) nsq += __shfl_xor(nsq, m, 16);
            inv = __fdividef(1.0f, sqrtf(nsq) + 1e-16f);
        }
    }

    // ---- f_fin ----
    float* fo = out + Bq * Oq + Bq * Hq + (size_t)b * Hq * Fq + rowoff;
#pragma unroll
    for (int j = 0; j < 8; ++j) {
        const int c = 4 * lr + 64 * j;
        *(float4*)(fo + c) = *(const float4*)&ff[4*j];
    }
}

// tag_space = h_fin @ out_w.T + out_b. 16-lane group per output; coalesced
// 1KB-span dwordx4 reads of out_w rows; h_fin cached in regs across outputs.
__global__ __launch_bounds__(256) void stpn_tag(
    const float* __restrict__ ow, const float* __restrict__ ob,
    float* __restrict__ out)
{
    const int b   = blockIdx.x;
    const int tid = threadIdx.x;
    const int l   = tid & 15;          // lane in group
    const int g   = tid >> 4;          // group 0..15
    const float* hf = out + Bq * Oq + (size_t)b * Hq + l * 16;
    const float4 h0 = ((const float4*)hf)[0];
    const float4 h1 = ((const float4*)hf)[1];
    const float4 h2 = ((const float4*)hf)[2];
    const float4 h3 = ((const float4*)hf)[3];
#pragma unroll
    for (int p = 0; p < 8; ++p) {
        const int o = g * 8 + p;
        const float* wr = ow + (size_t)o * Hq + l * 16;
        const float4 w0 = ((const float4*)wr)[0];
        const float4 w1 = ((const float4*)wr)[1];
        const float4 w2 = ((const float4*)wr)[2];
        const float4 w3 = ((const float4*)wr)[3];
        float acc = h0.x*w0.x + h0.y*w0.y + h0.z*w0.z + h0.w*w0.w
                  + h1.x*w1.x + h1.y*w1.y + h1.z*w1.z + h1.w*w1.w
                  + h2.x*w2.x + h2.y*w2.y + h2.z*w2.z + h2.w*w2.w
                  + h3.x*w3.x + h3.y*w3.y + h3.z*w3.z + h3.w*w3.w;
#pragma unroll
        for (int m = 1; m < 16; m <<= 1) acc += __shfl_xor(acc, m, 16);
        if (l == 0) out[b * Oq + o] = acc + ob[o];
    }
}

extern "C" void kernel_launch(void* const* d_in, const int* in_sizes, int n_in,
                              void* d_out, int out_size, void* d_ws, size_t ws_size,
                              hipStream_t stream)
{
    const float* x    = (const float*)d_in[0];
    const float* w    = (const float*)d_in[1];
    const float* wl   = (const float*)d_in[2];
    const float* wgm  = (const float*)d_in[3];
    const float* bias = (const float*)d_in[4];
    const float* ow   = (const float*)d_in[5];
    const float* ob   = (const float*)d_in[6];
    float* out = (float*)d_out;

    // Zero the (tag,val) h-exchange slots: 2 * B * H * 8 bytes = 128 KB.
    hipMemsetAsync(d_ws, 0, 2 * Bq * Hq * sizeof(unsigned long long), stream);

    stpn_main<<<Bq * WPB, NT, 0, stream>>>(x, w, wl, wgm, bias, out,
                                           (unsigned long long*)d_ws);
    stpn_tag<<<Bq, 256, 0, stream>>>(ow, ob, out);
}

// Round 4
// 182.183 us; speedup vs baseline: 1.0900x; 1.0900x over previous
//
#include <hip/hip_runtime.h>

// Problem dims (fixed by reference)
#define Bq 32
#define Sq 64
#define Iq 256
#define Hq 256
#define Oq 128
#define Fq 512          // Iq + Hq
#define WPB 8           // workgroups per batch
#define NT 512          // threads per workgroup

// tanh via v_exp_f32: 1 - 2/(e^{2x}+1). Saturates to +/-1 at +/-inf (no NaN).
__device__ __forceinline__ float fast_tanh(float v) {
    const float e = __expf(2.0f * v);
    return 1.0f - __fdividef(2.0f, e + 1.0f);
}

// R2 skeleton (measured 95us main) + three isolated deltas:
//  (a) inv (=1/norm) precomputed in the loop tail -- it depends only on f_t,
//      not on h_{t-1}; critical path after h arrives is pre-fma + butterfly +
//      tanh + publish. NO extra carried arrays (R3's regression): tw=fw+ff is
//      recomputed where needed, ti re-read from LDS.
//  (b) fast_tanh instead of tanhf libcall.
//  (c) tag GEMM fused: all wgs publish at t=63 (tag 64); chunk-0 wg polls it,
//      writes h_fin and computes tag_space. Separate kernel removed.
// Back-pressure safety of publish tag t+1 to parity p=t&1: reaching critical-t
// means staging-t observed tag t from ALL peers => every peer passed its
// barrier-(t-1) => every parity-p poll for tag t-1 has completed. Inductive,
// holds for t=63 too.
__global__ __launch_bounds__(NT, 2) void stpn_main(
    const float* __restrict__ x,     // (B,S,I)
    const float* __restrict__ w,     // (H,F)
    const float* __restrict__ wl,    // (H,F)
    const float* __restrict__ wgm,   // (H,F)
    const float* __restrict__ bias,  // (H)
    const float* __restrict__ ow,    // (O,H)
    const float* __restrict__ ob,    // (O)
    float* __restrict__ out,         // [tag(B*O) | h_fin(B*H) | f_fin(B*H*F)]
    unsigned long long* __restrict__ hb) // [2][B][H] (tag<<32|bits) slots
{
    const int blk   = blockIdx.x;
    const int b     = blk & 31;       // same-batch wgs round-robin onto XCDs
    const int chunk = blk >> 5;       // 0..7
    const int h0    = chunk * 32;
    const int tid   = threadIdx.x;
    const int lr    = tid & 15;       // lane within row
    const int r     = tid >> 4;       // row 0..31
    const int row   = h0 + r;

    __shared__ float ti[2][Fq];       // double-buffered total_input

    // Static params + fast-weight state in registers for all 64 steps.
    float fw[32], fl[32], fg[32], ff[32];
    const size_t rowoff = (size_t)row * Fq;
#pragma unroll
    for (int j = 0; j < 8; ++j) {
        const int c = 4 * lr + 64 * j;
        *(float4*)&fw[4*j] = *(const float4*)(w   + rowoff + c);
        *(float4*)&fl[4*j] = *(const float4*)(wl  + rowoff + c);
        *(float4*)&fg[4*j] = *(const float4*)(wgm + rowoff + c);
    }
#pragma unroll
    for (int j = 0; j < 32; ++j) ff[j] = 0.f;

    const float brow = bias[row];
    const float* xb = x + (size_t)b * Sq * Iq;

    // inv for t=0: norm of w row (f=0).
    float nsq = 0.f;
#pragma unroll
    for (int j = 0; j < 32; ++j) nsq = fmaf(fw[j], fw[j], nsq);
#pragma unroll
    for (int m = 1; m < 16; m <<= 1) nsq += __shfl_xor(nsq, m, 16);
    float inv = __fdividef(1.0f, sqrtf(nsq) + 1e-16f);

    for (int t = 0; t < Sq; ++t) {
        const int p = t & 1;
        // ---- staging: total_input = [x_t | h_{t-1}] into LDS parity p ----
        if (tid < Iq) {
            ti[p][tid] = xb[(size_t)t * Iq + tid];
        } else {
            const int hh = tid - Iq;
            float hv = 0.f;
            if (t > 0) {
                unsigned long long* slot =
                    hb + (size_t)((t - 1) & 1) * Bq * Hq + (size_t)b * Hq + hh;
                unsigned long long v;
                do {
                    v = __hip_atomic_load(slot, __ATOMIC_RELAXED,
                                          __HIP_MEMORY_SCOPE_AGENT);
                } while ((unsigned)(v >> 32) != (unsigned)t);
                hv = __uint_as_float((unsigned)(v & 0xffffffffu));
            }
            ti[p][Iq + hh] = hv;
        }
        __syncthreads();                 // the only barrier per step

        // ---- critical: pre -> butterfly -> tanh -> publish ----
        float pre = 0.f;
#pragma unroll
        for (int j = 0; j < 8; ++j) {
            const float4 tv = *(const float4*)&ti[p][4 * lr + 64 * j];
            pre = fmaf(tv.x, fw[4*j+0] + ff[4*j+0], pre);
            pre = fmaf(tv.y, fw[4*j+1] + ff[4*j+1], pre);
            pre = fmaf(tv.z, fw[4*j+2] + ff[4*j+2], pre);
            pre = fmaf(tv.w, fw[4*j+3] + ff[4*j+3], pre);
        }
#pragma unroll
        for (int m = 1; m < 16; m <<= 1) pre += __shfl_xor(pre, m, 16);
        const float hn = fast_tanh(fmaf(pre, inv, brow));

        if (lr == 0) {
            const unsigned long long pk =
                ((unsigned long long)(unsigned)(t + 1) << 32) |
                (unsigned long long)__float_as_uint(hn);
            __hip_atomic_store(
                hb + (size_t)p * Bq * Hq + (size_t)b * Hq + row, pk,
                __ATOMIC_RELAXED, __HIP_MEMORY_SCOPE_AGENT);
        }

        // ---- shadow: f update, then inv for step t+1 ----
#pragma unroll
        for (int j = 0; j < 8; ++j) {
            const float4 tv = *(const float4*)&ti[p][4 * lr + 64 * j];
            ff[4*j+0] = fmaf(fl[4*j+0], ff[4*j+0] * inv, fg[4*j+0] * (hn * tv.x));
            ff[4*j+1] = fmaf(fl[4*j+1], ff[4*j+1] * inv, fg[4*j+1] * (hn * tv.y));
            ff[4*j+2] = fmaf(fl[4*j+2], ff[4*j+2] * inv, fg[4*j+2] * (hn * tv.z));
            ff[4*j+3] = fmaf(fl[4*j+3], ff[4*j+3] * inv, fg[4*j+3] * (hn * tv.w));
        }
        if (t < Sq - 1) {
            nsq = 0.f;
#pragma unroll
            for (int j = 0; j < 32; ++j) {
                const float tw = fw[j] + ff[j];
                nsq = fmaf(tw, tw, nsq);
            }
#pragma unroll
            for (int m = 1; m < 16; m <<= 1) nsq += __shfl_xor(nsq, m, 16);
            inv = __fdividef(1.0f, sqrtf(nsq) + 1e-16f);
        }
    }

    // ---- f_fin: 16 lanes x float4 per row chunk ----
    float* fo = out + Bq * Oq + Bq * Hq + (size_t)b * Hq * Fq + rowoff;
#pragma unroll
    for (int j = 0; j < 8; ++j) {
        const int c = 4 * lr + 64 * j;
        *(float4*)(fo + c) = *(const float4*)&ff[4*j];
    }

    // ---- epilogue (chunk-0 wg per batch): h_fin + tag_space ----
    if (chunk == 0) {
        if (tid < Hq) {
            unsigned long long* slot =
                hb + (size_t)1 * Bq * Hq + (size_t)b * Hq + tid;  // t=63 -> parity 1
            unsigned long long v;
            do {
                v = __hip_atomic_load(slot, __ATOMIC_RELAXED,
                                      __HIP_MEMORY_SCOPE_AGENT);
            } while ((unsigned)(v >> 32) != (unsigned)Sq);
            const float hv = __uint_as_float((unsigned)(v & 0xffffffffu));
            ti[0][tid] = hv;
            out[Bq * Oq + (size_t)b * Hq + tid] = hv;   // h_fin
        }
        __syncthreads();
        // 512 threads = 128 outputs x 4 lanes; each lane sums 64 elems.
        const int o = tid >> 2;
        const int l = tid & 3;
        const float* wr = ow + (size_t)o * Hq + l * 64;
        float acc = 0.f;
#pragma unroll
        for (int k = 0; k < 16; ++k) {
            const float4 w4 = ((const float4*)wr)[k];
            const float4 h4 = *(const float4*)&ti[0][l * 64 + 4 * k];
            acc += w4.x * h4.x + w4.y * h4.y + w4.z * h4.z + w4.w * h4.w;
        }
        acc += __shfl_xor(acc, 1, 4);
        acc += __shfl_xor(acc, 2, 4);
        if (l == 0) out[(size_t)b * Oq + o] = acc + ob[o];
    }
}

extern "C" void kernel_launch(void* const* d_in, const int* in_sizes, int n_in,
                              void* d_out, int out_size, void* d_ws, size_t ws_size,
                              hipStream_t stream)
{
    const float* x    = (const float*)d_in[0];
    const float* w    = (const float*)d_in[1];
    const float* wl   = (const float*)d_in[2];
    const float* wgm  = (const float*)d_in[3];
    const float* bias = (const float*)d_in[4];
    const float* ow   = (const float*)d_in[5];
    const float* ob   = (const float*)d_in[6];
    float* out = (float*)d_out;

    // Zero the (tag,val) h-exchange slots: 2 * B * H * 8 bytes = 128 KB.
    // (Poison 0xAA.. never matches a live tag, but first-call d_ws contents
    // are unspecified -- keep the cheap memset for safety.)
    hipMemsetAsync(d_ws, 0, 2 * Bq * Hq * sizeof(unsigned long long), stream);

    stpn_main<<<Bq * WPB, NT, 0, stream>>>(x, w, wl, wgm, bias, ow, ob, out,
                                           (unsigned long long*)d_ws);
}

// Round 5
// 154.331 us; speedup vs baseline: 1.2867x; 1.1805x over previous
//
#include <hip/hip_runtime.h>

// Problem dims (fixed by reference)
#define Bq 32
#define Sq 64
#define Iq 256
#define Hq 256
#define Oq 128
#define Fq 512          // Iq + Hq
#define WPB 8           // workgroups per batch
#define NT 512          // threads per workgroup
#define PRE_S 56        // steps with x preloaded in LDS (56KB; total LDS 60KB < 64KB)

// R2 skeleton (measured-best 97us main) with the loop body FROZEN:
// fused pre+nsq critical loop, inv + tanhf in critical, f-update shadow.
// R3/R4 both proved that splitting nsq/inv out of the critical loop REGRESSES
// (97 -> 129 / 122 us) regardless of register pressure -- do not reintroduce.
// Deltas vs R2, both outside the per-step serial structure:
//  (a) x_0..x_55 preloaded to LDS in the prologue; staging is poll-only for
//      t < 56 (x-threads reach the barrier immediately).
//  (b) epilogue fused: all wgs publish at t=63 (tag 64); chunk-0 wg polls,
//      writes h_fin, computes tag_space (bank-conflict-free layout).
__global__ __launch_bounds__(NT, 2) void stpn_main(
    const float* __restrict__ x,     // (B,S,I)
    const float* __restrict__ w,     // (H,F)
    const float* __restrict__ wl,    // (H,F)
    const float* __restrict__ wgm,   // (H,F)
    const float* __restrict__ bias,  // (H)
    const float* __restrict__ ow,    // (O,H)
    const float* __restrict__ ob,    // (O)
    float* __restrict__ out,         // [tag(B*O) | h_fin(B*H) | f_fin(B*H*F)]
    unsigned long long* __restrict__ hb) // [2][B][H] (tag<<32|bits) slots
{
    const int blk   = blockIdx.x;
    const int b     = blk & 31;       // all 8 wgs of a batch -> same XCD (blk%8 == b%8)
    const int chunk = blk >> 5;       // 0..7
    const int h0    = chunk * 32;
    const int tid   = threadIdx.x;
    const int lr    = tid & 15;       // lane within row
    const int r     = tid >> 4;       // row 0..31
    const int row   = h0 + r;

    __shared__ float ti[2][Fq];           // staging buf: x (t>=PRE_S) | h_{t-1}
    __shared__ float xall[PRE_S * Iq];    // x_0..x_55

    // Static params + fast-weight state in registers for all 64 steps.
    float fw[32], fl[32], fg[32], ff[32];
    const size_t rowoff = (size_t)row * Fq;
#pragma unroll
    for (int j = 0; j < 8; ++j) {
        const int c = 4 * lr + 64 * j;
        *(float4*)&fw[4*j] = *(const float4*)(w   + rowoff + c);
        *(float4*)&fl[4*j] = *(const float4*)(wl  + rowoff + c);
        *(float4*)&fg[4*j] = *(const float4*)(wgm + rowoff + c);
    }
#pragma unroll
    for (int j = 0; j < 32; ++j) ff[j] = 0.f;

    // Prologue x preload: 56*256/4 = 3584 float4 = 512 threads x 7.
    {
        const float4* xs = (const float4*)(x + (size_t)b * Sq * Iq);
        float4* xd = (float4*)xall;
#pragma unroll
        for (int k = 0; k < (PRE_S * Iq / 4) / NT; ++k)
            xd[tid + NT * k] = xs[tid + NT * k];
    }
    const float brow = bias[row];
    const float* xb = x + (size_t)b * Sq * Iq;

    for (int t = 0; t < Sq; ++t) {
        const int p = t & 1;
        // ---- staging: poll h_{t-1}; x only for the non-preloaded tail ----
        if (tid < Iq) {
            if (t >= PRE_S) ti[p][tid] = xb[(size_t)t * Iq + tid];
        } else {
            const int hh = tid - Iq;
            float hv = 0.f;
            if (t > 0) {
                unsigned long long* slot =
                    hb + (size_t)((t - 1) & 1) * Bq * Hq + (size_t)b * Hq + hh;
                unsigned long long v;
                do {
                    v = __hip_atomic_load(slot, __ATOMIC_RELAXED,
                                          __HIP_MEMORY_SCOPE_AGENT);
                } while ((unsigned)(v >> 32) != (unsigned)t);
                hv = __uint_as_float((unsigned)(v & 0xffffffffu));
            }
            ti[p][Iq + hh] = hv;
        }
        __syncthreads();                 // the only barrier per step
        // (covers prologue preload -> first read at t=0 too)

        const float* xpart = (t < PRE_S) ? (xall + t * Iq) : &ti[p][0];
        const float* hpart = &ti[p][Iq];

        // ---- critical: fused pre+nsq -> butterflies -> inv -> tanh -> publish
        float pre = 0.f, nsq = 0.f;
#pragma unroll
        for (int j = 0; j < 4; ++j) {
            const float4 tv = *(const float4*)&xpart[4 * lr + 64 * j];
            float tw;
            tw = fw[4*j+0] + ff[4*j+0]; pre = fmaf(tv.x, tw, pre); nsq = fmaf(tw, tw, nsq);
            tw = fw[4*j+1] + ff[4*j+1]; pre = fmaf(tv.y, tw, pre); nsq = fmaf(tw, tw, nsq);
            tw = fw[4*j+2] + ff[4*j+2]; pre = fmaf(tv.z, tw, pre); nsq = fmaf(tw, tw, nsq);
            tw = fw[4*j+3] + ff[4*j+3]; pre = fmaf(tv.w, tw, pre); nsq = fmaf(tw, tw, nsq);
        }
#pragma unroll
        for (int j = 4; j < 8; ++j) {
            const float4 tv = *(const float4*)&hpart[4 * lr + 64 * (j - 4)];
            float tw;
            tw = fw[4*j+0] + ff[4*j+0]; pre = fmaf(tv.x, tw, pre); nsq = fmaf(tw, tw, nsq);
            tw = fw[4*j+1] + ff[4*j+1]; pre = fmaf(tv.y, tw, pre); nsq = fmaf(tw, tw, nsq);
            tw = fw[4*j+2] + ff[4*j+2]; pre = fmaf(tv.z, tw, pre); nsq = fmaf(tw, tw, nsq);
            tw = fw[4*j+3] + ff[4*j+3]; pre = fmaf(tv.w, tw, pre); nsq = fmaf(tw, tw, nsq);
        }
#pragma unroll
        for (int m = 1; m < 16; m <<= 1) {
            pre += __shfl_xor(pre, m, 16);
            nsq += __shfl_xor(nsq, m, 16);
        }
        const float inv = __fdividef(1.0f, sqrtf(nsq) + 1e-16f);
        const float hn  = tanhf(fmaf(pre, inv, brow));

        if (lr == 0) {
            const unsigned long long pk =
                ((unsigned long long)(unsigned)(t + 1) << 32) |
                (unsigned long long)__float_as_uint(hn);
            __hip_atomic_store(
                hb + (size_t)p * Bq * Hq + (size_t)b * Hq + row, pk,
                __ATOMIC_RELAXED, __HIP_MEMORY_SCOPE_AGENT);
        }

        // ---- shadow: f update ----
#pragma unroll
        for (int j = 0; j < 4; ++j) {
            const float4 tv = *(const float4*)&xpart[4 * lr + 64 * j];
            ff[4*j+0] = fmaf(fl[4*j+0], ff[4*j+0] * inv, fg[4*j+0] * (hn * tv.x));
            ff[4*j+1] = fmaf(fl[4*j+1], ff[4*j+1] * inv, fg[4*j+1] * (hn * tv.y));
            ff[4*j+2] = fmaf(fl[4*j+2], ff[4*j+2] * inv, fg[4*j+2] * (hn * tv.z));
            ff[4*j+3] = fmaf(fl[4*j+3], ff[4*j+3] * inv, fg[4*j+3] * (hn * tv.w));
        }
#pragma unroll
        for (int j = 4; j < 8; ++j) {
            const float4 tv = *(const float4*)&hpart[4 * lr + 64 * (j - 4)];
            ff[4*j+0] = fmaf(fl[4*j+0], ff[4*j+0] * inv, fg[4*j+0] * (hn * tv.x));
            ff[4*j+1] = fmaf(fl[4*j+1], ff[4*j+1] * inv, fg[4*j+1] * (hn * tv.y));
            ff[4*j+2] = fmaf(fl[4*j+2], ff[4*j+2] * inv, fg[4*j+2] * (hn * tv.z));
            ff[4*j+3] = fmaf(fl[4*j+3], ff[4*j+3] * inv, fg[4*j+3] * (hn * tv.w));
        }
    }

    // ---- f_fin: 16 lanes x float4 per row chunk ----
    float* fo = out + Bq * Oq + Bq * Hq + (size_t)b * Hq * Fq + rowoff;
#pragma unroll
    for (int j = 0; j < 8; ++j) {
        const int c = 4 * lr + 64 * j;
        *(float4*)(fo + c) = *(const float4*)&ff[4*j];
    }

    // ---- epilogue (chunk-0 wg per batch): h_fin + tag_space ----
    if (chunk == 0) {
        if (tid < Hq) {
            unsigned long long* slot =
                hb + (size_t)1 * Bq * Hq + (size_t)b * Hq + tid;  // t=63 -> parity 1
            unsigned long long v;
            do {
                v = __hip_atomic_load(slot, __ATOMIC_RELAXED,
                                      __HIP_MEMORY_SCOPE_AGENT);
            } while ((unsigned)(v >> 32) != (unsigned)Sq);
            const float hv = __uint_as_float((unsigned)(v & 0xffffffffu));
            ti[0][tid] = hv;                              // ti[0] is free here
            out[Bq * Oq + (size_t)b * Hq + tid] = hv;     // h_fin
        }
        __syncthreads();
        // 512 threads = 128 outputs x 4 lanes; lane l sums cols 16k+4l..+3.
        // LDS: 4 distinct 16B reads per quad at banks 4l.. -> conflict-free.
        const int o = tid >> 2;
        const int l = tid & 3;
        const float* wr = ow + (size_t)o * Hq;
        float acc = 0.f;
#pragma unroll
        for (int k = 0; k < 16; ++k) {
            const int cc = 16 * k + 4 * l;
            const float4 w4 = *(const float4*)(wr + cc);
            const float4 h4 = *(const float4*)&ti[0][cc];
            acc += w4.x * h4.x + w4.y * h4.y + w4.z * h4.z + w4.w * h4.w;
        }
        acc += __shfl_xor(acc, 1, 4);
        acc += __shfl_xor(acc, 2, 4);
        if (l == 0) out[(size_t)b * Oq + o] = acc + ob[o];
    }
}

extern "C" void kernel_launch(void* const* d_in, const int* in_sizes, int n_in,
                              void* d_out, int out_size, void* d_ws, size_t ws_size,
                              hipStream_t stream)
{
    const float* x    = (const float*)d_in[0];
    const float* w    = (const float*)d_in[1];
    const float* wl   = (const float*)d_in[2];
    const float* wgm  = (const float*)d_in[3];
    const float* bias = (const float*)d_in[4];
    const float* ow   = (const float*)d_in[5];
    const float* ob   = (const float*)d_in[6];
    float* out = (float*)d_out;

    // Zero the (tag,val) h-exchange slots: 2 * B * H * 8 bytes = 128 KB.
    hipMemsetAsync(d_ws, 0, 2 * Bq * Hq * sizeof(unsigned long long), stream);

    stpn_main<<<Bq * WPB, NT, 0, stream>>>(x, w, wl, wgm, bias, ow, ob, out,
                                           (unsigned long long*)d_ws);
}